// Round 3
// baseline (243.772 us; speedup 1.0000x reference)
//
#include <hip/hip_runtime.h>
#include <hip/hip_bf16.h>

#define NNODE 1024
#define DIM 128
#define HEADS 8
#define DK 16
#define EDIM 16
#define TM 32          // source nodes per chunk
#define BN 8           // target nodes per attn block
#define MS 4           // m-range splits
#define CH ((NNODE / MS) / TM)   // chunks per block = 8
#define KSTRIDE 132    // k/v LDS row stride (floats): 128+4, 16B-aligned, conflict-free
#define EFSTRIDE 20    // ef LDS row stride (floats)
#define PSTRIDE 33     // partial: sl + accv[16] + accT[16]

// ---------------- Kernel 1: LayerNorm + QKV projection ----------------
__global__ __launch_bounds__(384)
void ln_qkv_kernel(const float* __restrict__ x,
                   const float* __restrict__ Wq, const float* __restrict__ bq,
                   const float* __restrict__ Wk, const float* __restrict__ bk,
                   const float* __restrict__ Wv, const float* __restrict__ bv,
                   const float* __restrict__ gamma, const float* __restrict__ beta,
                   float* __restrict__ qg, float* __restrict__ kg, float* __restrict__ vg) {
    const int n = blockIdx.x;
    const int t = threadIdx.x;
    __shared__ float hrow[DIM];
    __shared__ float part[4];

    float xv = 0.f;
    if (t < 128) {
        xv = x[n * DIM + t];
        float v = xv;
        #pragma unroll
        for (int off = 32; off >= 1; off >>= 1) v += __shfl_xor(v, off);
        if ((t & 63) == 0) part[t >> 6] = v;
    }
    __syncthreads();
    const float mu = (part[0] + part[1]) * (1.0f / DIM);
    const float dx = xv - mu;
    if (t < 128) {
        float v = dx * dx;
        #pragma unroll
        for (int off = 32; off >= 1; off >>= 1) v += __shfl_xor(v, off);
        if ((t & 63) == 0) part[2 + (t >> 6)] = v;
    }
    __syncthreads();
    if (t < 128) {
        const float var = (part[2] + part[3]) * (1.0f / DIM);
        hrow[t] = dx * rsqrtf(var + 1e-5f) * gamma[t] + beta[t];
    }
    __syncthreads();

    const int which = t >> 7;          // 0,1,2 -> q,k,v (wave-uniform)
    const int col = t & 127;
    const float* W = (which == 0) ? Wq : (which == 1) ? Wk : Wv;
    const float* b = (which == 0) ? bq : (which == 1) ? bk : bv;
    float* o       = (which == 0) ? qg : (which == 1) ? kg : vg;
    float acc = b[col];
    #pragma unroll 16
    for (int i = 0; i < DIM; ++i) acc = fmaf(hrow[i], W[i * DIM + col], acc);
    o[n * DIM + col] = acc;
}

// ---------------- Kernel 2: attention partials ----------------
// grid = (NNODE/BN)*MS = 512 blocks; 256 threads = (n: t>>5, h: (t>>2)&7, s: t&3)
// Block covers target nodes [n0, n0+8) x source range [ms*256, ms*256+256),
// k/v chunk staged in LDS once and reused by all 8 target nodes.
__global__ __launch_bounds__(256, 2)
void attn_kernel(const float* __restrict__ qg, const float* __restrict__ kg,
                 const float* __restrict__ vg, const float* __restrict__ ef,
                 const int* __restrict__ mask,
                 const float* __restrict__ Wae, const float* __restrict__ bae,
                 float* __restrict__ part) {
    const int t = threadIdx.x;
    const int n = t >> 5;          // 0..7 target-node slot
    const int h = (t >> 2) & 7;    // head
    const int s = t & 3;           // m sub-slot
    const int n0 = (blockIdx.x >> 2) * BN;
    const int ms = blockIdx.x & 3;
    const int mstart = ms * (NNODE / MS);

    __shared__ float ef_lds[BN * TM * EFSTRIDE];  // 20.0 KB
    __shared__ float k_lds[TM * KSTRIDE];         // 16.5 KB
    __shared__ float v_lds[TM * KSTRIDE];         // 16.5 KB
    __shared__ int   mk_lds[BN * 33];             // 1.03 KB

    // staging index plan (constant per thread)
    int ef_nn[4], ef_mm[4], ef_e4[4], kv_mm[4], kv_c4[4];
    #pragma unroll
    for (int r = 0; r < 4; ++r) {
        const int u = t + 256 * r;
        ef_nn[r] = u >> 7;
        ef_mm[r] = (u & 127) >> 2;
        ef_e4[r] = (u & 3) * 4;
        kv_mm[r] = u >> 5;
        kv_c4[r] = (u & 31) * 4;
    }
    const int mk_nn = t >> 5, mk_mm = t & 31;

    // per-thread constants
    float qreg[DK];
    {
        const float* qp = qg + (size_t)(n0 + n) * DIM + h * DK;
        #pragma unroll
        for (int d4 = 0; d4 < 4; ++d4) {
            float4 qv = *(const float4*)(qp + d4 * 4);
            qreg[d4 * 4 + 0] = qv.x; qreg[d4 * 4 + 1] = qv.y;
            qreg[d4 * 4 + 2] = qv.z; qreg[d4 * 4 + 3] = qv.w;
        }
    }
    float waec[EDIM];
    #pragma unroll
    for (int e = 0; e < EDIM; ++e) waec[e] = Wae[e * HEADS + h];
    const float baeh = bae[h];

    float sl = 0.f, accv[DK], accT[EDIM];
    #pragma unroll
    for (int d = 0; d < DK; ++d) accv[d] = 0.f;
    #pragma unroll
    for (int e = 0; e < EDIM; ++e) accT[e] = 0.f;

    // prefetch registers
    float4 pf_ef[4], pf_k[4], pf_v[4];
    int pf_mk;

    // load chunk 0
    {
        const int mb = mstart;
        #pragma unroll
        for (int r = 0; r < 4; ++r) {
            pf_ef[r] = *(const float4*)(ef + ((size_t)(n0 + ef_nn[r]) * NNODE + mb + ef_mm[r]) * EDIM + ef_e4[r]);
            pf_k[r]  = *(const float4*)(kg + (size_t)(mb + kv_mm[r]) * DIM + kv_c4[r]);
            pf_v[r]  = *(const float4*)(vg + (size_t)(mb + kv_mm[r]) * DIM + kv_c4[r]);
        }
        pf_mk = mask[(size_t)(n0 + mk_nn) * NNODE + mb + mk_mm];
    }

    for (int c = 0; c < CH; ++c) {
        __syncthreads();   // previous chunk's LDS consumers done
        #pragma unroll
        for (int r = 0; r < 4; ++r) {
            *(float4*)&ef_lds[(ef_nn[r] * TM + ef_mm[r]) * EFSTRIDE + ef_e4[r]] = pf_ef[r];
            *(float4*)&k_lds[kv_mm[r] * KSTRIDE + kv_c4[r]] = pf_k[r];
            *(float4*)&v_lds[kv_mm[r] * KSTRIDE + kv_c4[r]] = pf_v[r];
        }
        mk_lds[mk_nn * 33 + mk_mm] = pf_mk;
        __syncthreads();   // staging visible

        // issue next chunk's global loads (latency hidden behind compute)
        if (c + 1 < CH) {
            const int mb = mstart + (c + 1) * TM;
            #pragma unroll
            for (int r = 0; r < 4; ++r) {
                pf_ef[r] = *(const float4*)(ef + ((size_t)(n0 + ef_nn[r]) * NNODE + mb + ef_mm[r]) * EDIM + ef_e4[r]);
                pf_k[r]  = *(const float4*)(kg + (size_t)(mb + kv_mm[r]) * DIM + kv_c4[r]);
                pf_v[r]  = *(const float4*)(vg + (size_t)(mb + kv_mm[r]) * DIM + kv_c4[r]);
            }
            pf_mk = mask[(size_t)(n0 + mk_nn) * NNODE + mb + mk_mm];
        }

        // compute: this thread covers m = 4j+s for its (n, h)
        #pragma unroll
        for (int j = 0; j < 8; ++j) {
            const int mm = 4 * j + s;
            float kk[DK], vv[DK], efv[EDIM];
            const float* kp = &k_lds[mm * KSTRIDE + h * DK];
            const float* vp = &v_lds[mm * KSTRIDE + h * DK];
            const float* ep = &ef_lds[(n * TM + mm) * EFSTRIDE];
            #pragma unroll
            for (int d4 = 0; d4 < 4; ++d4) {
                float4 k4 = *(const float4*)(kp + d4 * 4);
                kk[d4 * 4 + 0] = k4.x; kk[d4 * 4 + 1] = k4.y;
                kk[d4 * 4 + 2] = k4.z; kk[d4 * 4 + 3] = k4.w;
                float4 v4 = *(const float4*)(vp + d4 * 4);
                vv[d4 * 4 + 0] = v4.x; vv[d4 * 4 + 1] = v4.y;
                vv[d4 * 4 + 2] = v4.z; vv[d4 * 4 + 3] = v4.w;
                float4 e4 = *(const float4*)(ep + d4 * 4);
                efv[d4 * 4 + 0] = e4.x; efv[d4 * 4 + 1] = e4.y;
                efv[d4 * 4 + 2] = e4.z; efv[d4 * 4 + 3] = e4.w;
            }
            float bias = baeh, dot = 0.f;
            #pragma unroll
            for (int e = 0; e < EDIM; ++e) bias = fmaf(efv[e], waec[e], bias);
            #pragma unroll
            for (int d = 0; d < DK; ++d) dot = fmaf(qreg[d], kk[d], dot);
            const float logit = dot * 0.25f + bias;   // 1/sqrt(16)
            // masked -> exp(-10000) == 0 in fp32, identical to reference
            const float p = mk_lds[n * 33 + mm] ? __expf(logit) : 0.f;
            sl += p;
            #pragma unroll
            for (int d = 0; d < DK; ++d) accv[d] = fmaf(p, vv[d], accv[d]);
            #pragma unroll
            for (int e = 0; e < EDIM; ++e) accT[e] = fmaf(p, efv[e], accT[e]);
        }
    }

    // reduce over the 4 s-lanes (lane bits 0..1)
    #pragma unroll
    for (int off = 1; off <= 2; off <<= 1) {
        sl += __shfl_xor(sl, off);
        #pragma unroll
        for (int d = 0; d < DK; ++d) accv[d] += __shfl_xor(accv[d], off);
        #pragma unroll
        for (int e = 0; e < EDIM; ++e) accT[e] += __shfl_xor(accT[e], off);
    }
    if (s == 0) {
        float* p = part + (((size_t)(n0 + n) * MS + ms) * HEADS + h) * PSTRIDE;
        p[0] = sl;
        #pragma unroll
        for (int d = 0; d < DK; ++d) p[1 + d] = accv[d];
        #pragma unroll
        for (int e = 0; e < EDIM; ++e) p[17 + e] = accT[e];
    }
}

// ---------------- Kernel 3: combine partials + Wve epilogue + Wo proj + residual ----------------
__global__ __launch_bounds__(128)
void combine_kernel(const float* __restrict__ part,
                    const float* __restrict__ Wve, const float* __restrict__ bve,
                    const float* __restrict__ x,
                    const float* __restrict__ Wo, const float* __restrict__ bo,
                    float* __restrict__ out) {
    const int n = blockIdx.x;
    const int t = threadIdx.x;
    __shared__ float pb[MS * HEADS * PSTRIDE];   // 1056 floats
    __shared__ float cT[HEADS][EDIM];
    __shared__ float csl[HEADS];
    __shared__ float orow[DIM];

    for (int u = t; u < MS * HEADS * PSTRIDE; u += 128)
        pb[u] = part[(size_t)n * MS * HEADS * PSTRIDE + u];
    __syncthreads();

    {   // t in [0,128): exactly HEADS*EDIM slots for cT
        const int hh = t >> 4, e = t & 15;
        float v = 0.f;
        #pragma unroll
        for (int m = 0; m < MS; ++m) v += pb[(m * HEADS + hh) * PSTRIDE + 17 + e];
        cT[hh][e] = v;
        if (t < HEADS) {
            float sv = 0.f;
            #pragma unroll
            for (int m = 0; m < MS; ++m) sv += pb[(m * HEADS + t) * PSTRIDE];
            csl[t] = sv;
        }
    }
    __syncthreads();

    const int col = t;
    const int hh = col >> 4, dd = col & 15;
    float av = 0.f;
    #pragma unroll
    for (int m = 0; m < MS; ++m) av += pb[(m * HEADS + hh) * PSTRIDE + 1 + dd];
    float acc2 = 0.f;
    #pragma unroll
    for (int e = 0; e < EDIM; ++e) acc2 = fmaf(cT[hh][e], Wve[e * DIM + col], acc2);
    orow[col] = (av + acc2) / csl[hh] + bve[col];
    __syncthreads();

    float acc = bo[col] + x[(size_t)n * DIM + col];
    #pragma unroll 16
    for (int i = 0; i < DIM; ++i) acc = fmaf(orow[i], Wo[i * DIM + col], acc);
    out[(size_t)n * DIM + col] = acc;
}

extern "C" void kernel_launch(void* const* d_in, const int* in_sizes, int n_in,
                              void* d_out, int out_size, void* d_ws, size_t ws_size,
                              hipStream_t stream) {
    const float* x     = (const float*)d_in[0];
    const float* ef    = (const float*)d_in[1];
    const int*   mask  = (const int*)d_in[2];
    const float* Wq    = (const float*)d_in[3];
    const float* bq    = (const float*)d_in[4];
    const float* Wk    = (const float*)d_in[5];
    const float* bk    = (const float*)d_in[6];
    const float* Wv    = (const float*)d_in[7];
    const float* bv    = (const float*)d_in[8];
    const float* Wae   = (const float*)d_in[9];
    const float* bae   = (const float*)d_in[10];
    const float* Wve   = (const float*)d_in[11];
    const float* bve   = (const float*)d_in[12];
    const float* Wo    = (const float*)d_in[13];
    const float* bo    = (const float*)d_in[14];
    const float* gamma = (const float*)d_in[15];
    const float* beta  = (const float*)d_in[16];

    float* ws = (float*)d_ws;
    float* qg   = ws;
    float* kg   = ws + (size_t)NNODE * DIM;
    float* vg   = ws + (size_t)2 * NNODE * DIM;
    float* partb = ws + (size_t)3 * NNODE * DIM;  // 1024*4*8*33 floats = 4.3 MB

    ln_qkv_kernel<<<NNODE, 384, 0, stream>>>(x, Wq, bq, Wk, bk, Wv, bv, gamma, beta, qg, kg, vg);
    attn_kernel<<<(NNODE / BN) * MS, 256, 0, stream>>>(qg, kg, vg, ef, mask, Wae, bae, partb);
    combine_kernel<<<NNODE, 128, 0, stream>>>(partb, Wve, bve, x, Wo, bo, (float*)d_out);
}